// Round 5
// baseline (666.032 us; speedup 1.0000x reference)
//
#include <hip/hip_runtime.h>
#include <math.h>

#define N_NODES 10000
#define IN_FEAT 512
#define OUT_FEAT 64
#define LRELU_ALPHA 0.2f
#define HUB_THRESH 0.01f
#define BITS_WORDS 320   // ceil(10000/32)=313, padded to 320 (10 iters x 32 words)
#define ROWS_PB 4        // rows per block in k2
#define CAND_CAP 512     // per-row per-chunk list; overflow falls back to LDS atomics (exact)

// workspace layout, in 32-bit words
#define WH_OFF   0          // Wh [10000*64]
#define ESRC_OFF 640000     // e_src [10000]
#define EDST_OFF 650000     // e_dst [10000]
#define T_OFF    660000     // t_j = hub[j]*0.01 [10000]
#define LT_OFF   670000     // log(t_j) [10000]
// total ~2.7 MB

// ---------------------------------------------------------------------------
// Kernel 1: Wh = h @ W  (10000x512x64), e_src = Wh@a_src, e_dst = Wh@a_dst,
// plus (in trailing blocks) t_j and log(t_j) from hub_mask.
// ---------------------------------------------------------------------------
__global__ __launch_bounds__(256) void k1_gemm(
    const float* __restrict__ h, const float* __restrict__ W,
    const float* __restrict__ a_src, const float* __restrict__ a_dst,
    const float* __restrict__ hub, float* __restrict__ ws)
{
    const int bx = blockIdx.x, tid = threadIdx.x;
    if (bx >= 625) {
        const int base = (bx - 625) * 1024;
        #pragma unroll
        for (int e = 0; e < 4; ++e) {
            int idx = base + e * 256 + tid;
            if (idx < N_NODES) {
                float t = hub[idx] * HUB_THRESH;
                ws[T_OFF + idx]  = t;
                ws[LT_OFF + idx] = logf(t);   // hub==0 -> -inf: prefilter passes, relu decides
            }
        }
        return;
    }

    __shared__ __align__(16) float Ws[64 * 64];   // [kk][col]
    __shared__ __align__(16) float Hs[16 * 64];   // [r][kk]
    const int col = tid & 63, rg = tid >> 6;
    const int rowBase = bx * 16;                  // 625*16 == 10000 exactly
    float acc[4] = {0.f, 0.f, 0.f, 0.f};

    for (int k0 = 0; k0 < IN_FEAT; k0 += 64) {
        for (int idx = tid; idx < 4096; idx += 256) {
            int kk = idx >> 6, c = idx & 63;
            Ws[idx] = W[(size_t)(k0 + kk) * 64 + c];
        }
        for (int idx = tid; idx < 1024; idx += 256) {
            int r = idx >> 6, kk = idx & 63;
            Hs[idx] = h[(size_t)(rowBase + r) * IN_FEAT + k0 + kk];
        }
        __syncthreads();
        #pragma unroll
        for (int k4 = 0; k4 < 16; ++k4) {
            float4 hv0 = *(const float4*)&Hs[(rg + 0)  * 64 + k4 * 4];
            float4 hv1 = *(const float4*)&Hs[(rg + 4)  * 64 + k4 * 4];
            float4 hv2 = *(const float4*)&Hs[(rg + 8)  * 64 + k4 * 4];
            float4 hv3 = *(const float4*)&Hs[(rg + 12) * 64 + k4 * 4];
            float w0 = Ws[(k4 * 4 + 0) * 64 + col];
            float w1 = Ws[(k4 * 4 + 1) * 64 + col];
            float w2 = Ws[(k4 * 4 + 2) * 64 + col];
            float w3 = Ws[(k4 * 4 + 3) * 64 + col];
            acc[0] += hv0.x * w0 + hv0.y * w1 + hv0.z * w2 + hv0.w * w3;
            acc[1] += hv1.x * w0 + hv1.y * w1 + hv1.z * w2 + hv1.w * w3;
            acc[2] += hv2.x * w0 + hv2.y * w1 + hv2.z * w2 + hv2.w * w3;
            acc[3] += hv3.x * w0 + hv3.y * w1 + hv3.z * w2 + hv3.w * w3;
        }
        __syncthreads();
    }

    const float asv = a_src[col], adv = a_dst[col];
    #pragma unroll
    for (int r = 0; r < 4; ++r) {
        int row = rowBase + rg + 4 * r;
        ws[WH_OFF + (size_t)row * 64 + col] = acc[r];
        float s1 = acc[r] * asv, s2 = acc[r] * adv;
        #pragma unroll
        for (int m = 32; m; m >>= 1) {
            s1 += __shfl_xor(s1, m, 64);
            s2 += __shfl_xor(s2, m, 64);
        }
        if (col == 0) {
            ws[ESRC_OFF + row] = s1;
            ws[EDST_OFF + row] = s2;
        }
    }
}

// ---------------------------------------------------------------------------
// Kernel 2 (fused, 4 rows/block): block b handles rows 4b..4b+3.
// Pass A: stream 4 adj rows once (400 MB total across grid), one shared edst
// float4 per chunk; l_r = sum_{adj>0} exp(lrelu(esrc_r + edst_j)); bits->LDS.
// Pass B: ONE shared nibble scan per 4 rows; log-domain prefilter; survivors
// into per-row LDS lists (cap 512; overflow -> exact LDS-atomic accumulation);
// waves split lists: broadcast LDS read + coalesced L2-hit Wh load + FMA.
// LDS ~22.8 KB -> 7 blocks/CU (28 waves). Epilogue aliases `bits`.
// ---------------------------------------------------------------------------
__global__ __launch_bounds__(256) void k2_fused(
    const int* __restrict__ adj, const float* __restrict__ ws,
    float* __restrict__ out)
{
    const int b = blockIdx.x, tid = threadIdx.x;
    const int lane = tid & 63, w = tid >> 6;
    const int i0 = ROWS_PB * b;
    __shared__ unsigned bits[ROWS_PB][BITS_WORDS];   // 5120 B; aliased as partB (4 KB) in epilogue
    __shared__ float partA[ROWS_PB][4];
    __shared__ int2  cand[ROWS_PB][CAND_CAP];        // 16 KB
    __shared__ int   cnt[ROWS_PB][10];               // per-chunk counters
    __shared__ float oaccL[ROWS_PB][64];             // overflow accumulator (exact fallback)

    const float* __restrict__ edst = ws + EDST_OFF;
    float esrc[ROWS_PB];
    const int4* arow[ROWS_PB];
    float acc[ROWS_PB];
    #pragma unroll
    for (int r = 0; r < ROWS_PB; ++r) {
        esrc[r] = ws[ESRC_OFF + i0 + r];
        arow[r] = (const int4*)(adj + (size_t)(i0 + r) * N_NODES);  // 40000 B rows: 16B aligned
        acc[r] = 0.f;
    }
    if (tid < ROWS_PB * 10) ((int*)cnt)[tid] = 0;
    ((float*)oaccL)[tid] = 0.f;                      // 4*64 == 256 == blockDim

    // ---- Pass A: stream 4 adj rows once ----
    #pragma unroll 2
    for (int it = 0; it < 10; ++it) {
        const int j0 = it * 1024 + tid * 4;
        unsigned nib[ROWS_PB] = {0, 0, 0, 0};
        if (j0 < N_NODES) {   // N%4==0 -> full int4 whenever j0<N
            float4 e4 = *(const float4*)(edst + j0);
            float s0 = 0, s1 = 0, s2 = 0, s3 = 0;
            #pragma unroll
            for (int r = 0; r < ROWS_PB; ++r) {
                int4 a4 = arow[r][j0 >> 2];
                float s, e;
                s = esrc[r] + e4.x; e = fmaxf(s, LRELU_ALPHA * s);
                if (a4.x > 0) { acc[r] += __expf(e); nib[r] |= 1u; }
                s = esrc[r] + e4.y; e = fmaxf(s, LRELU_ALPHA * s);
                if (a4.y > 0) { acc[r] += __expf(e); nib[r] |= 2u; }
                s = esrc[r] + e4.z; e = fmaxf(s, LRELU_ALPHA * s);
                if (a4.z > 0) { acc[r] += __expf(e); nib[r] |= 4u; }
                s = esrc[r] + e4.w; e = fmaxf(s, LRELU_ALPHA * s);
                if (a4.w > 0) { acc[r] += __expf(e); nib[r] |= 8u; }
            }
            (void)s0; (void)s1; (void)s2; (void)s3;
        }
        // pack 8 lanes x 4 bits -> one word per row; each word written once;
        // pad bits (j>=10000) are 0 via the nib guard.
        #pragma unroll
        for (int r = 0; r < ROWS_PB; ++r) {
            unsigned v = nib[r] << ((lane & 7) * 4);
            v |= (unsigned)__shfl_xor((int)v, 1, 64);
            v |= (unsigned)__shfl_xor((int)v, 2, 64);
            v |= (unsigned)__shfl_xor((int)v, 4, 64);
            if ((lane & 7) == 0) bits[r][j0 >> 5] = v;
        }
    }

    #pragma unroll
    for (int r = 0; r < ROWS_PB; ++r) {
        float a = acc[r];
        #pragma unroll
        for (int m = 32; m; m >>= 1) a += __shfl_xor(a, m, 64);
        if (lane == 0) partA[r][w] = a;
    }
    __syncthreads();

    // ---- Pass B ----
    float l[ROWS_PB], cl[ROWS_PB], thr[ROWS_PB];
    bool empty[ROWS_PB];
    bool anyEmpty = false;
    #pragma unroll
    for (int r = 0; r < ROWS_PB; ++r) {
        l[r] = partA[r][0] + partA[r][1] + partA[r][2] + partA[r][3];
        empty[r] = (l[r] == 0.0f);               // row w/o neighbors: softmax uniform 1/N
        anyEmpty |= empty[r];
        cl[r] = empty[r] ? 0.0f : logf(l[r]);
        thr[r] = cl[r] - 0.0625f;                // prefilter slack
    }
    const float invN = 1.0f / (float)N_NODES;
    const float* __restrict__ tarr  = ws + T_OFF;
    const float* __restrict__ ltarr = ws + LT_OFF;
    const float* __restrict__ Wh    = ws + WH_OFF;
    float oacc[ROWS_PB] = {0.f, 0.f, 0.f, 0.f};

    for (int it = 0; it < 10; ++it) {
        const int j0 = it * 1024 + tid * 4;
        unsigned m[ROWS_PB] = {0, 0, 0, 0};
        if (j0 < N_NODES) {
            #pragma unroll
            for (int r = 0; r < ROWS_PB; ++r)
                m[r] = empty[r] ? 0u : (bits[r][j0 >> 5] >> (j0 & 31)) & 0xFu;  // j0%32 mult of 4
        }
        if (m[0] | m[1] | m[2] | m[3]) {
            float4 e4  = *(const float4*)(edst + j0);
            float4 lt4 = *(const float4*)(ltarr + j0);
            #pragma unroll
            for (int c = 0; c < 4; ++c) {
                float ed = (c == 0) ? e4.x  : (c == 1) ? e4.y  : (c == 2) ? e4.z  : e4.w;
                float lt = (c == 0) ? lt4.x : (c == 1) ? lt4.y : (c == 2) ? lt4.z : lt4.w;
                #pragma unroll
                for (int r = 0; r < ROWS_PB; ++r) {
                    if (m[r] & (1u << c)) {
                        float s = esrc[r] + ed;
                        float e = fmaxf(s, LRELU_ALPHA * s);
                        if (e > thr[r] + lt) {                    // rare
                            float p = __expf(e - cl[r]);          // = exp(e)/l_r
                            float wgt = p - tarr[j0 + c];         // exact relu decides
                            if (wgt > 0.0f) {
                                int k = atomicAdd(&cnt[r][it], 1);
                                if (k < CAND_CAP) {
                                    cand[r][k] = make_int2(j0 + c, __float_as_int(wgt));
                                } else {   // exact fallback; never taken on plausible data
                                    const float* whp = Wh + (size_t)(j0 + c) * 64;
                                    for (int cc = 0; cc < 64; ++cc)
                                        atomicAdd(&oaccL[r][cc], wgt * whp[cc]);
                                }
                            }
                        }
                    }
                }
            }
        }
        if (anyEmpty && j0 < N_NODES) {   // block-uniform; dead for this data
            float4 t4 = *(const float4*)(tarr + j0);
            #pragma unroll
            for (int c = 0; c < 4; ++c) {
                float tv = (c == 0) ? t4.x : (c == 1) ? t4.y : (c == 2) ? t4.z : t4.w;
                float wv = invN - tv;
                if (wv > 0.0f) {
                    #pragma unroll
                    for (int r = 0; r < ROWS_PB; ++r) {
                        if (empty[r]) {
                            int k = atomicAdd(&cnt[r][it], 1);
                            if (k < CAND_CAP) {
                                cand[r][k] = make_int2(j0 + c, __float_as_int(wv));
                            } else {
                                const float* whp = Wh + (size_t)(j0 + c) * 64;
                                for (int cc = 0; cc < 64; ++cc)
                                    atomicAdd(&oaccL[r][cc], wv * whp[cc]);
                            }
                        }
                    }
                }
            }
        }
        __syncthreads();   // lists for chunk `it` complete
        #pragma unroll
        for (int r = 0; r < ROWS_PB; ++r) {
            const int M = min(cnt[r][it], CAND_CAP);
            for (int c = w; c < M; c += 4) {
                int2 cd = cand[r][c];                            // wave-uniform LDS broadcast
                oacc[r] += __int_as_float(cd.y) * Wh[(size_t)cd.x * 64 + lane];  // 256B coalesced, L2-hit
            }
        }
        __syncthreads();   // lists consumed before next chunk overwrites
    }

    // epilogue: alias bits (5120 B >= 1024 floats); barrier above fences reuse
    float* partB = (float*)bits;
    #pragma unroll
    for (int r = 0; r < ROWS_PB; ++r) partB[r * 256 + tid] = oacc[r];
    __syncthreads();
    {   // wave w handles row i0+w
        const float* pb = partB + w * 256;
        float tot = pb[lane] + pb[64 + lane] + pb[128 + lane] + pb[192 + lane]
                  + oaccL[w][lane];
        out[(size_t)(i0 + w) * 64 + lane] = tot > 0.0f ? tot : expm1f(tot);   // elu, alpha=1
    }
}

// ---------------------------------------------------------------------------
extern "C" void kernel_launch(void* const* d_in, const int* in_sizes, int n_in,
                              void* d_out, int out_size, void* d_ws, size_t ws_size,
                              hipStream_t stream)
{
    const float* h     = (const float*)d_in[0];
    const float* W     = (const float*)d_in[1];
    const float* a_src = (const float*)d_in[2];
    const float* a_dst = (const float*)d_in[3];
    const float* hub   = (const float*)d_in[4];
    const int*   adj   = (const int*)d_in[5];
    float* ws  = (float*)d_ws;
    float* out = (float*)d_out;

    k1_gemm<<<635, 256, 0, stream>>>(h, W, a_src, a_dst, hub, ws);
    k2_fused<<<N_NODES / ROWS_PB, 256, 0, stream>>>(adj, ws, out);
}

// Round 7
// 627.809 us; speedup vs baseline: 1.0609x; 1.0609x over previous
//
#include <hip/hip_runtime.h>
#include <math.h>

#define N_NODES 10000
#define IN_FEAT 512
#define OUT_FEAT 64
#define LRELU_ALPHA 0.2f
#define HUB_THRESH 0.01f
#define BITS_WORDS 320   // ceil(10000/32)=313, padded to 320 (10 iters x 32 words)
#define CAND_CAP 512     // per-row per-parity list; overflow -> exact LDS-atomic fallback

// workspace layout, in 32-bit words
#define WH_OFF   0          // Wh [10000*64]
#define ESRC_OFF 640000     // e_src [10000]
#define EDST_OFF 650000     // e_dst [10000]
#define T_OFF    660000     // t_j = hub[j]*0.01 [10000]
#define LT_OFF   670000     // log(t_j) [10000]
// total ~2.7 MB

// ---------------------------------------------------------------------------
// Kernel 1: Wh = h @ W  (10000x512x64), e_src = Wh@a_src, e_dst = Wh@a_dst,
// plus (in trailing blocks) t_j and log(t_j) from hub_mask.
// ---------------------------------------------------------------------------
__global__ __launch_bounds__(256) void k1_gemm(
    const float* __restrict__ h, const float* __restrict__ W,
    const float* __restrict__ a_src, const float* __restrict__ a_dst,
    const float* __restrict__ hub, float* __restrict__ ws)
{
    const int bx = blockIdx.x, tid = threadIdx.x;
    if (bx >= 625) {
        const int base = (bx - 625) * 1024;
        #pragma unroll
        for (int e = 0; e < 4; ++e) {
            int idx = base + e * 256 + tid;
            if (idx < N_NODES) {
                float t = hub[idx] * HUB_THRESH;
                ws[T_OFF + idx]  = t;
                ws[LT_OFF + idx] = logf(t);   // hub==0 -> -inf: prefilter passes, relu decides
            }
        }
        return;
    }

    __shared__ __align__(16) float Ws[64 * 64];   // [kk][col]
    __shared__ __align__(16) float Hs[16 * 64];   // [r][kk]
    const int col = tid & 63, rg = tid >> 6;
    const int rowBase = bx * 16;                  // 625*16 == 10000 exactly
    float acc[4] = {0.f, 0.f, 0.f, 0.f};

    for (int k0 = 0; k0 < IN_FEAT; k0 += 64) {
        for (int idx = tid; idx < 4096; idx += 256) {
            int kk = idx >> 6, c = idx & 63;
            Ws[idx] = W[(size_t)(k0 + kk) * 64 + c];
        }
        for (int idx = tid; idx < 1024; idx += 256) {
            int r = idx >> 6, kk = idx & 63;
            Hs[idx] = h[(size_t)(rowBase + r) * IN_FEAT + k0 + kk];
        }
        __syncthreads();
        #pragma unroll
        for (int k4 = 0; k4 < 16; ++k4) {
            float4 hv0 = *(const float4*)&Hs[(rg + 0)  * 64 + k4 * 4];
            float4 hv1 = *(const float4*)&Hs[(rg + 4)  * 64 + k4 * 4];
            float4 hv2 = *(const float4*)&Hs[(rg + 8)  * 64 + k4 * 4];
            float4 hv3 = *(const float4*)&Hs[(rg + 12) * 64 + k4 * 4];
            float w0 = Ws[(k4 * 4 + 0) * 64 + col];
            float w1 = Ws[(k4 * 4 + 1) * 64 + col];
            float w2 = Ws[(k4 * 4 + 2) * 64 + col];
            float w3 = Ws[(k4 * 4 + 3) * 64 + col];
            acc[0] += hv0.x * w0 + hv0.y * w1 + hv0.z * w2 + hv0.w * w3;
            acc[1] += hv1.x * w0 + hv1.y * w1 + hv1.z * w2 + hv1.w * w3;
            acc[2] += hv2.x * w0 + hv2.y * w1 + hv2.z * w2 + hv2.w * w3;
            acc[3] += hv3.x * w0 + hv3.y * w1 + hv3.z * w2 + hv3.w * w3;
        }
        __syncthreads();
    }

    const float asv = a_src[col], adv = a_dst[col];
    #pragma unroll
    for (int r = 0; r < 4; ++r) {
        int row = rowBase + rg + 4 * r;
        ws[WH_OFF + (size_t)row * 64 + col] = acc[r];
        float s1 = acc[r] * asv, s2 = acc[r] * adv;
        #pragma unroll
        for (int m = 32; m; m >>= 1) {
            s1 += __shfl_xor(s1, m, 64);
            s2 += __shfl_xor(s2, m, 64);
        }
        if (col == 0) {
            ws[ESRC_OFF + row] = s1;
            ws[EDST_OFF + row] = s2;
        }
    }
}

// ---------------------------------------------------------------------------
// Kernel 2 (fused, 2 rows/block): block b handles rows 2b, 2b+1.
// Pass A: stream both adj rows once (the 400 MB total), shared edst loads;
//   l_r = sum_{adj>0} exp(lrelu(esrc_r + edst_j)); bits packed into LDS.
// Pass B: shared nibble scan with FULL log-domain prefilter e > thr + lt_j
// (per-j lt is required: lt is unbounded below, no lt-free bound is valid —
// R6 lesson); survivors into DOUBLE-BUFFERED per-row lists (one barrier per
// chunk; cap 512 with exact LDS-atomic overflow fallback); waves split
// lists: broadcast LDS read + coalesced L2-hit Wh load + FMA.
// LDS ~19.6 KB -> 8 blocks/CU. Epilogue aliases `bits`.
// ---------------------------------------------------------------------------
__global__ __launch_bounds__(256) void k2_fused(
    const int* __restrict__ adj, const float* __restrict__ ws,
    float* __restrict__ out)
{
    const int b = blockIdx.x, tid = threadIdx.x;
    const int lane = tid & 63, w = tid >> 6;
    const int i0 = 2 * b, i1 = 2 * b + 1;
    __shared__ unsigned bits[2][BITS_WORDS];   // 2560 B; aliased as partB in epilogue
    __shared__ float partA[2][4];
    __shared__ int2  cand[2][2][CAND_CAP];     // [row][parity][k], 16 KB
    __shared__ int   cnt[2][10];               // per-row per-chunk counters
    __shared__ float oaccL[2][64];             // overflow accumulator (exact fallback)

    const float esrc0 = ws[ESRC_OFF + i0];
    const float esrc1 = ws[ESRC_OFF + i1];
    const float* __restrict__ edst = ws + EDST_OFF;
    const int4* __restrict__ arow0 = (const int4*)(adj + (size_t)i0 * N_NODES); // 40000 B rows: 16B aligned
    const int4* __restrict__ arow1 = (const int4*)(adj + (size_t)i1 * N_NODES);
    float acc0 = 0.f, acc1 = 0.f;

    if (tid < 20) ((int*)cnt)[tid] = 0;        // visible after pass-A barrier
    if (tid < 128) ((float*)oaccL)[tid] = 0.f;

    // ---- Pass A: stream both adj rows once ----
    #pragma unroll 2
    for (int it = 0; it < 10; ++it) {
        const int j0 = it * 1024 + tid * 4;
        unsigned nib0 = 0, nib1 = 0;
        if (j0 < N_NODES) {   // N%4==0 -> full int4 whenever j0<N
            int4 a0 = arow0[j0 >> 2];
            int4 a1 = arow1[j0 >> 2];
            float4 e4 = *(const float4*)(edst + j0);
            float s, e;
            s = esrc0 + e4.x; e = fmaxf(s, LRELU_ALPHA * s);
            if (a0.x > 0) { acc0 += __expf(e); nib0 |= 1u; }
            s = esrc0 + e4.y; e = fmaxf(s, LRELU_ALPHA * s);
            if (a0.y > 0) { acc0 += __expf(e); nib0 |= 2u; }
            s = esrc0 + e4.z; e = fmaxf(s, LRELU_ALPHA * s);
            if (a0.z > 0) { acc0 += __expf(e); nib0 |= 4u; }
            s = esrc0 + e4.w; e = fmaxf(s, LRELU_ALPHA * s);
            if (a0.w > 0) { acc0 += __expf(e); nib0 |= 8u; }
            s = esrc1 + e4.x; e = fmaxf(s, LRELU_ALPHA * s);
            if (a1.x > 0) { acc1 += __expf(e); nib1 |= 1u; }
            s = esrc1 + e4.y; e = fmaxf(s, LRELU_ALPHA * s);
            if (a1.y > 0) { acc1 += __expf(e); nib1 |= 2u; }
            s = esrc1 + e4.z; e = fmaxf(s, LRELU_ALPHA * s);
            if (a1.z > 0) { acc1 += __expf(e); nib1 |= 4u; }
            s = esrc1 + e4.w; e = fmaxf(s, LRELU_ALPHA * s);
            if (a1.w > 0) { acc1 += __expf(e); nib1 |= 8u; }
        }
        // pack 8 lanes x 4 bits -> one word per row; each word written once;
        // pad bits (j>=10000) are 0 via the nib guard.
        unsigned v0 = nib0 << ((lane & 7) * 4);
        unsigned v1 = nib1 << ((lane & 7) * 4);
        v0 |= (unsigned)__shfl_xor((int)v0, 1, 64);
        v1 |= (unsigned)__shfl_xor((int)v1, 1, 64);
        v0 |= (unsigned)__shfl_xor((int)v0, 2, 64);
        v1 |= (unsigned)__shfl_xor((int)v1, 2, 64);
        v0 |= (unsigned)__shfl_xor((int)v0, 4, 64);
        v1 |= (unsigned)__shfl_xor((int)v1, 4, 64);
        if ((lane & 7) == 0) {
            bits[0][j0 >> 5] = v0;
            bits[1][j0 >> 5] = v1;
        }
    }

    #pragma unroll
    for (int m = 32; m; m >>= 1) {
        acc0 += __shfl_xor(acc0, m, 64);
        acc1 += __shfl_xor(acc1, m, 64);
    }
    if (lane == 0) { partA[0][w] = acc0; partA[1][w] = acc1; }
    __syncthreads();
    const float l0 = partA[0][0] + partA[0][1] + partA[0][2] + partA[0][3];
    const float l1 = partA[1][0] + partA[1][1] + partA[1][2] + partA[1][3];

    // ---- Pass B ----
    const bool empty0 = (l0 == 0.0f), empty1 = (l1 == 0.0f);  // rows w/o neighbors: uniform 1/N
    const float cl0 = empty0 ? 0.0f : logf(l0);
    const float cl1 = empty1 ? 0.0f : logf(l1);
    const float thr0 = cl0 - 0.0625f, thr1 = cl1 - 0.0625f;   // prefilter slack
    const float invN = 1.0f / (float)N_NODES;
    const float* __restrict__ tarr  = ws + T_OFF;
    const float* __restrict__ ltarr = ws + LT_OFF;
    const float* __restrict__ Wh    = ws + WH_OFF;
    float oacc0 = 0.f, oacc1 = 0.f;

    for (int it = 0; it < 10; ++it) {
        const int buf = it & 1;
        const int j0 = it * 1024 + tid * 4;
        unsigned m0 = 0, m1 = 0;
        if (j0 < N_NODES) {
            m0 = empty0 ? 0u : (bits[0][j0 >> 5] >> (j0 & 31)) & 0xFu;  // j0%32 mult of 4
            m1 = empty1 ? 0u : (bits[1][j0 >> 5] >> (j0 & 31)) & 0xFu;
        }
        if (m0 | m1) {
            float4 e4  = *(const float4*)(edst + j0);
            float4 lt4 = *(const float4*)(ltarr + j0);
            #pragma unroll
            for (int c = 0; c < 4; ++c) {
                float ed = (c == 0) ? e4.x  : (c == 1) ? e4.y  : (c == 2) ? e4.z  : e4.w;
                float lt = (c == 0) ? lt4.x : (c == 1) ? lt4.y : (c == 2) ? lt4.z : lt4.w;
                if (m0 & (1u << c)) {
                    float s = esrc0 + ed;
                    float e = fmaxf(s, LRELU_ALPHA * s);
                    if (e > thr0 + lt) {                      // rare
                        float p = __expf(e - cl0);            // = exp(e)/l0
                        float wgt = p - tarr[j0 + c];         // exact relu decides
                        if (wgt > 0.0f) {
                            int k = atomicAdd(&cnt[0][it], 1);
                            if (k < CAND_CAP) {
                                cand[0][buf][k] = make_int2(j0 + c, __float_as_int(wgt));
                            } else {   // exact fallback; never taken on plausible data
                                const float* whp = Wh + (size_t)(j0 + c) * 64;
                                for (int cc = 0; cc < 64; ++cc)
                                    atomicAdd(&oaccL[0][cc], wgt * whp[cc]);
                            }
                        }
                    }
                }
                if (m1 & (1u << c)) {
                    float s = esrc1 + ed;
                    float e = fmaxf(s, LRELU_ALPHA * s);
                    if (e > thr1 + lt) {
                        float p = __expf(e - cl1);
                        float wgt = p - tarr[j0 + c];
                        if (wgt > 0.0f) {
                            int k = atomicAdd(&cnt[1][it], 1);
                            if (k < CAND_CAP) {
                                cand[1][buf][k] = make_int2(j0 + c, __float_as_int(wgt));
                            } else {
                                const float* whp = Wh + (size_t)(j0 + c) * 64;
                                for (int cc = 0; cc < 64; ++cc)
                                    atomicAdd(&oaccL[1][cc], wgt * whp[cc]);
                            }
                        }
                    }
                }
            }
        }
        if ((empty0 | empty1) && j0 < N_NODES) {   // block-uniform; dead for this data
            float4 t4 = *(const float4*)(tarr + j0);
            #pragma unroll
            for (int c = 0; c < 4; ++c) {
                float tv = (c == 0) ? t4.x : (c == 1) ? t4.y : (c == 2) ? t4.z : t4.w;
                float wv = invN - tv;
                if (wv > 0.0f) {
                    #pragma unroll
                    for (int r = 0; r < 2; ++r) {
                        if (r == 0 ? empty0 : empty1) {
                            int k = atomicAdd(&cnt[r][it], 1);
                            if (k < CAND_CAP) {
                                cand[r][buf][k] = make_int2(j0 + c, __float_as_int(wv));
                            } else {
                                const float* whp = Wh + (size_t)(j0 + c) * 64;
                                for (int cc = 0; cc < 64; ++cc)
                                    atomicAdd(&oaccL[r][cc], wv * whp[cc]);
                            }
                        }
                    }
                }
            }
        }
        __syncthreads();   // lists for chunk `it` complete
        const int M0 = min(cnt[0][it], CAND_CAP), M1 = min(cnt[1][it], CAND_CAP);
        for (int c = w; c < M0; c += 4) {
            int2 cd = cand[0][buf][c];                       // wave-uniform LDS broadcast
            oacc0 += __int_as_float(cd.y) * Wh[(size_t)cd.x * 64 + lane];  // 256B coalesced, L2-hit
        }
        for (int c = w; c < M1; c += 4) {
            int2 cd = cand[1][buf][c];
            oacc1 += __int_as_float(cd.y) * Wh[(size_t)cd.x * 64 + lane];
        }
        // no second barrier: a wave racing ahead produces chunk it+1 into the
        // OTHER parity buffer (own atomic slot in cnt[r][it+1]), then waits at
        // that chunk's barrier; this buffer is only overwritten at chunk it+2,
        // strictly after barrier(it+1) which follows everyone's consume(it).
    }

    // epilogue: alias bits (2560 B >= 512 floats). Safe: every wave passed
    // barrier(9), which guarantees all produce-phase reads of `bits` are done.
    float* partB = (float*)bits;
    partB[tid]       = oacc0;
    partB[256 + tid] = oacc1;
    __syncthreads();
    if (w < 2) {
        const float* pb = partB + w * 256;
        float tot = pb[lane] + pb[64 + lane] + pb[128 + lane] + pb[192 + lane]
                  + oaccL[w][lane];
        out[(size_t)(i0 + w) * 64 + lane] = tot > 0.0f ? tot : expm1f(tot);   // elu, alpha=1
    }
}

// ---------------------------------------------------------------------------
extern "C" void kernel_launch(void* const* d_in, const int* in_sizes, int n_in,
                              void* d_out, int out_size, void* d_ws, size_t ws_size,
                              hipStream_t stream)
{
    const float* h     = (const float*)d_in[0];
    const float* W     = (const float*)d_in[1];
    const float* a_src = (const float*)d_in[2];
    const float* a_dst = (const float*)d_in[3];
    const float* hub   = (const float*)d_in[4];
    const int*   adj   = (const int*)d_in[5];
    float* ws  = (float*)d_ws;
    float* out = (float*)d_out;

    k1_gemm<<<635, 256, 0, stream>>>(h, W, a_src, a_dst, hub, ws);
    k2_fused<<<N_NODES / 2, 256, 0, stream>>>(adj, ws, out);
}